// Round 8
// baseline (91.052 us; speedup 1.0000x reference)
//
#include <hip/hip_runtime.h>
#include <hip/hip_cooperative_groups.h>

namespace cg = cooperative_groups;

// Problem constants (fixed by the reference)
constexpr int N    = 16384;
constexpr int K    = 32;
constexpr int D    = 128;
constexpr int SPAD = K + 2;       // LDS score row stride (34)

// ---- DPP helpers: butterfly add over 16-lane groups, pure VALU ----
template <int CTRL>
__device__ __forceinline__ float dpp_add(float v) {
    int j = __builtin_amdgcn_update_dpp(0, __float_as_int(v), CTRL, 0xF, 0xF, false);
    return v + __int_as_float(j);
}
__device__ __forceinline__ float sum16(float v) {
    v = dpp_add<0xB1>(v);    // quad_perm xor1
    v = dpp_add<0x4E>(v);    // quad_perm xor2
    v = dpp_add<0x141>(v);   // row_half_mirror
    v = dpp_add<0x140>(v);   // row_mirror
    return v;                // 16-lane sum in every lane of the group
}

// ------------------------------------------------------------------
// Single cooperative kernel: 512 blocks x 256 threads (2 blocks/CU).
// Phase A: each block computes partial E over its 32 rows (4 chunks
//   of 8 reg-resident rows; DPP distance reduce; LDS only for
//   scores/weights) -> ws[block][K*D]  (8 MB total).
// grid.sync()
// Phase B: block b column-sums ws[0..511][cols 8b..8b+7] -> out.
// One dispatch, no atomics, no memset.
// ------------------------------------------------------------------
constexpr int CGRID  = 512;
constexpr int CROWS  = N / CGRID;     // 32 rows per block
constexpr int CHUNK  = 8;
constexpr int NCHUNK = CROWS / CHUNK; // 4

__global__ __launch_bounds__(256, 2) void enc_coop(
    const float* __restrict__ x,      // (N, D)
    const float* __restrict__ codes,  // (K, D)
    const float* __restrict__ scale,  // (K,)
    float* __restrict__ ws,           // (CGRID, K*D)
    float* __restrict__ out)          // (K, D)
{
    __shared__ float sc_lds[CHUNK][SPAD];
    __shared__ float w_lds[CHUNK][SPAD];
    __shared__ float4 part[128][2];    // phase-B scratch (4 KB)

    const int tid = threadIdx.x;
    const int kg  = tid >> 4;    // 0..15 -> k0 = 2kg
    const int dg  = tid & 15;    // 0..15
    const int d4  = dg << 2;     // float4 at d4 and 64+d4
    const int k0  = kg << 1;

    // codes fragments (2 k's x 2 float4s) + scales, in registers throughout
    const float4 cA0 = *reinterpret_cast<const float4*>(&codes[k0 * D + d4]);
    const float4 cA1 = *reinterpret_cast<const float4*>(&codes[k0 * D + 64 + d4]);
    const float4 cB0 = *reinterpret_cast<const float4*>(&codes[(k0 + 1) * D + d4]);
    const float4 cB1 = *reinterpret_cast<const float4*>(&codes[(k0 + 1) * D + 64 + d4]);
    const float sA = scale[k0];
    const float sB = scale[k0 + 1];

    // persistent partial accumulators across chunks
    float4 tA0 = make_float4(0.f, 0.f, 0.f, 0.f);
    float4 tA1 = tA0, tB0 = tA0, tB1 = tA0;
    float swA = 0.f, swB = 0.f;

    const float* xb = x + (long)blockIdx.x * CROWS * D;

    for (int c = 0; c < NCHUNK; ++c) {
        // ---- x chunk into registers: 8 rows x 2 float4 per thread ----
        float4 xr[CHUNK][2];
        const float* xc = xb + c * CHUNK * D;
        #pragma unroll
        for (int n = 0; n < CHUNK; ++n) {
            xr[n][0] = *reinterpret_cast<const float4*>(xc + n * D + d4);
            xr[n][1] = *reinterpret_cast<const float4*>(xc + n * D + 64 + d4);
        }

        // ---- Phase 1: scores ----
        #pragma unroll
        for (int n = 0; n < CHUNK; ++n) {
            const float4 xa = xr[n][0];
            const float4 xb4 = xr[n][1];
            float r;
            float pA0 = 0.f, pA1 = 0.f, pB0 = 0.f, pB1 = 0.f;
            r = xa.x - cA0.x;  pA0 = fmaf(r, r, pA0);
            r = xa.y - cA0.y;  pA1 = fmaf(r, r, pA1);
            r = xa.z - cA0.z;  pA0 = fmaf(r, r, pA0);
            r = xa.w - cA0.w;  pA1 = fmaf(r, r, pA1);
            r = xb4.x - cA1.x; pA0 = fmaf(r, r, pA0);
            r = xb4.y - cA1.y; pA1 = fmaf(r, r, pA1);
            r = xb4.z - cA1.z; pA0 = fmaf(r, r, pA0);
            r = xb4.w - cA1.w; pA1 = fmaf(r, r, pA1);
            r = xa.x - cB0.x;  pB0 = fmaf(r, r, pB0);
            r = xa.y - cB0.y;  pB1 = fmaf(r, r, pB1);
            r = xa.z - cB0.z;  pB0 = fmaf(r, r, pB0);
            r = xa.w - cB0.w;  pB1 = fmaf(r, r, pB1);
            r = xb4.x - cB1.x; pB0 = fmaf(r, r, pB0);
            r = xb4.y - cB1.y; pB1 = fmaf(r, r, pB1);
            r = xb4.z - cB1.z; pB0 = fmaf(r, r, pB0);
            r = xb4.w - cB1.w; pB1 = fmaf(r, r, pB1);
            float pA = sum16(pA0 + pA1);
            float pB = sum16(pB0 + pB1);
            if (dg == 0) {
                sc_lds[n][k0]     = sqrtf(pA) * sA;
                sc_lds[n][k0 + 1] = sqrtf(pB) * sB;
            }
        }
        __syncthreads();

        // ---- Softmax over K per row: 32 threads/row ----
        {
            const int row = tid >> 5;      // 0..7
            const int q   = tid & 31;
            float s = sc_lds[row][q];
            float m = s;
            m = fmaxf(m, __shfl_xor(m, 1));
            m = fmaxf(m, __shfl_xor(m, 2));
            m = fmaxf(m, __shfl_xor(m, 4));
            m = fmaxf(m, __shfl_xor(m, 8));
            m = fmaxf(m, __shfl_xor(m, 16));
            const float LOG2E = 1.44269504088896f;
            float e = exp2f((s - m) * LOG2E);
            float sum = e;
            sum += __shfl_xor(sum, 1);
            sum += __shfl_xor(sum, 2);
            sum += __shfl_xor(sum, 4);
            sum += __shfl_xor(sum, 8);
            sum += __shfl_xor(sum, 16);
            w_lds[row][q] = e * (1.0f / sum);
        }
        __syncthreads();

        // ---- Phase 2: accumulate T and S ----
        #pragma unroll
        for (int n = 0; n < CHUNK; ++n) {
            const float2 w = *reinterpret_cast<const float2*>(&w_lds[n][k0]);
            const float4 xa = xr[n][0];
            const float4 xb4 = xr[n][1];
            tA0.x = fmaf(w.x, xa.x, tA0.x);
            tA0.y = fmaf(w.x, xa.y, tA0.y);
            tA0.z = fmaf(w.x, xa.z, tA0.z);
            tA0.w = fmaf(w.x, xa.w, tA0.w);
            tA1.x = fmaf(w.x, xb4.x, tA1.x);
            tA1.y = fmaf(w.x, xb4.y, tA1.y);
            tA1.z = fmaf(w.x, xb4.z, tA1.z);
            tA1.w = fmaf(w.x, xb4.w, tA1.w);
            tB0.x = fmaf(w.y, xa.x, tB0.x);
            tB0.y = fmaf(w.y, xa.y, tB0.y);
            tB0.z = fmaf(w.y, xa.z, tB0.z);
            tB0.w = fmaf(w.y, xa.w, tB0.w);
            tB1.x = fmaf(w.y, xb4.x, tB1.x);
            tB1.y = fmaf(w.y, xb4.y, tB1.y);
            tB1.z = fmaf(w.y, xb4.z, tB1.z);
            tB1.w = fmaf(w.y, xb4.w, tB1.w);
            swA += w.x;
            swB += w.y;
        }
        __syncthreads();   // protect sc_lds/w_lds before next chunk
    }

    // ---- Phase-A epilogue: partial E_b = T - S*c -> ws (dense stores) ----
    {
        float* o = ws + (long)blockIdx.x * (K * D) + k0 * D + d4;
        *reinterpret_cast<float4*>(o)       = make_float4(tA0.x - swA * cA0.x, tA0.y - swA * cA0.y,
                                                          tA0.z - swA * cA0.z, tA0.w - swA * cA0.w);
        *reinterpret_cast<float4*>(o + 64)  = make_float4(tA1.x - swA * cA1.x, tA1.y - swA * cA1.y,
                                                          tA1.z - swA * cA1.z, tA1.w - swA * cA1.w);
        *reinterpret_cast<float4*>(o + 128) = make_float4(tB0.x - swB * cB0.x, tB0.y - swB * cB0.y,
                                                          tB0.z - swB * cB0.z, tB0.w - swB * cB0.w);
        *reinterpret_cast<float4*>(o + 192) = make_float4(tB1.x - swB * cB1.x, tB1.y - swB * cB1.y,
                                                          tB1.z - swB * cB1.z, tB1.w - swB * cB1.w);
    }

    cg::this_grid().sync();

    // ---- Phase B: column-sum ws[512][4096] -> out[4096] ----
    // Block owns 2 float4-cols; thread: col=tid&1, slice=tid>>1 (128 x 4 rows).
    {
        const int col   = tid & 1;
        const int slice = tid >> 1;               // 0..127
        const int gcol  = blockIdx.x * 2 + col;   // 0..1023
        const float4* P = reinterpret_cast<const float4*>(ws);  // [512][1024]
        float4 acc = make_float4(0.f, 0.f, 0.f, 0.f);
        #pragma unroll
        for (int r = 0; r < 4; ++r) {
            float4 v = P[(long)(slice * 4 + r) * 1024 + gcol];
            acc.x += v.x; acc.y += v.y; acc.z += v.z; acc.w += v.w;
        }
        part[slice][col] = acc;
        __syncthreads();
        #pragma unroll
        for (int stride = 64; stride >= 1; stride >>= 1) {
            if (tid < stride * 2) {
                float4 a = part[slice][col];
                float4 b = part[slice + stride][col];
                a.x += b.x; a.y += b.y; a.z += b.z; a.w += b.w;
                part[slice][col] = a;
            }
            __syncthreads();
        }
        if (tid < 2) {
            reinterpret_cast<float4*>(out)[blockIdx.x * 2 + tid] = part[0][tid];
        }
    }
}

// ------------------------------------------------------------------
// Fallback two-kernel path (R7): used if cooperative launch fails
// or ws is too small for the coop path's needs but fits 32 MB.
// ------------------------------------------------------------------
constexpr int ROWS1 = 8;
constexpr int GRID1 = N / ROWS1;  // 2048

__global__ __launch_bounds__(256) void enc_partial(
    const float* __restrict__ x,
    const float* __restrict__ codes,
    const float* __restrict__ scale,
    float* __restrict__ ws)
{
    __shared__ float sc_lds[ROWS1][SPAD];
    __shared__ float w_lds[ROWS1][SPAD];

    const int tid = threadIdx.x;
    const int kg  = tid >> 4;
    const int dg  = tid & 15;
    const int d4  = dg << 2;
    const int k0  = kg << 1;

    const float* xb = x + (long)blockIdx.x * ROWS1 * D;
    float4 xr[ROWS1][2];
    #pragma unroll
    for (int n = 0; n < ROWS1; ++n) {
        xr[n][0] = *reinterpret_cast<const float4*>(xb + n * D + d4);
        xr[n][1] = *reinterpret_cast<const float4*>(xb + n * D + 64 + d4);
    }

    const float4 cA0 = *reinterpret_cast<const float4*>(&codes[k0 * D + d4]);
    const float4 cA1 = *reinterpret_cast<const float4*>(&codes[k0 * D + 64 + d4]);
    const float4 cB0 = *reinterpret_cast<const float4*>(&codes[(k0 + 1) * D + d4]);
    const float4 cB1 = *reinterpret_cast<const float4*>(&codes[(k0 + 1) * D + 64 + d4]);
    const float sA = scale[k0];
    const float sB = scale[k0 + 1];

    #pragma unroll
    for (int n = 0; n < ROWS1; ++n) {
        const float4 xa = xr[n][0];
        const float4 xb4 = xr[n][1];
        float r;
        float pA0 = 0.f, pA1 = 0.f, pB0 = 0.f, pB1 = 0.f;
        r = xa.x - cA0.x;  pA0 = fmaf(r, r, pA0);
        r = xa.y - cA0.y;  pA1 = fmaf(r, r, pA1);
        r = xa.z - cA0.z;  pA0 = fmaf(r, r, pA0);
        r = xa.w - cA0.w;  pA1 = fmaf(r, r, pA1);
        r = xb4.x - cA1.x; pA0 = fmaf(r, r, pA0);
        r = xb4.y - cA1.y; pA1 = fmaf(r, r, pA1);
        r = xb4.z - cA1.z; pA0 = fmaf(r, r, pA0);
        r = xb4.w - cA1.w; pA1 = fmaf(r, r, pA1);
        r = xa.x - cB0.x;  pB0 = fmaf(r, r, pB0);
        r = xa.y - cB0.y;  pB1 = fmaf(r, r, pB1);
        r = xa.z - cB0.z;  pB0 = fmaf(r, r, pB0);
        r = xa.w - cB0.w;  pB1 = fmaf(r, r, pB1);
        r = xb4.x - cB1.x; pB0 = fmaf(r, r, pB0);
        r = xb4.y - cB1.y; pB1 = fmaf(r, r, pB1);
        r = xb4.z - cB1.z; pB0 = fmaf(r, r, pB0);
        r = xb4.w - cB1.w; pB1 = fmaf(r, r, pB1);
        float pA = sum16(pA0 + pA1);
        float pB = sum16(pB0 + pB1);
        if (dg == 0) {
            sc_lds[n][k0]     = sqrtf(pA) * sA;
            sc_lds[n][k0 + 1] = sqrtf(pB) * sB;
        }
    }
    __syncthreads();

    {
        const int row = tid >> 5;
        const int q   = tid & 31;
        float s = sc_lds[row][q];
        float m = s;
        m = fmaxf(m, __shfl_xor(m, 1));
        m = fmaxf(m, __shfl_xor(m, 2));
        m = fmaxf(m, __shfl_xor(m, 4));
        m = fmaxf(m, __shfl_xor(m, 8));
        m = fmaxf(m, __shfl_xor(m, 16));
        const float LOG2E = 1.44269504088896f;
        float e = exp2f((s - m) * LOG2E);
        float sum = e;
        sum += __shfl_xor(sum, 1);
        sum += __shfl_xor(sum, 2);
        sum += __shfl_xor(sum, 4);
        sum += __shfl_xor(sum, 8);
        sum += __shfl_xor(sum, 16);
        w_lds[row][q] = e * (1.0f / sum);
    }
    __syncthreads();

    float4 tA0 = make_float4(0.f, 0.f, 0.f, 0.f);
    float4 tA1 = tA0, tB0 = tA0, tB1 = tA0;
    float swA = 0.f, swB = 0.f;
    #pragma unroll
    for (int n = 0; n < ROWS1; ++n) {
        const float2 w = *reinterpret_cast<const float2*>(&w_lds[n][k0]);
        const float4 xa = xr[n][0];
        const float4 xb4 = xr[n][1];
        tA0.x = fmaf(w.x, xa.x, tA0.x);
        tA0.y = fmaf(w.x, xa.y, tA0.y);
        tA0.z = fmaf(w.x, xa.z, tA0.z);
        tA0.w = fmaf(w.x, xa.w, tA0.w);
        tA1.x = fmaf(w.x, xb4.x, tA1.x);
        tA1.y = fmaf(w.x, xb4.y, tA1.y);
        tA1.z = fmaf(w.x, xb4.z, tA1.z);
        tA1.w = fmaf(w.x, xb4.w, tA1.w);
        tB0.x = fmaf(w.y, xa.x, tB0.x);
        tB0.y = fmaf(w.y, xa.y, tB0.y);
        tB0.z = fmaf(w.y, xa.z, tB0.z);
        tB0.w = fmaf(w.y, xa.w, tB0.w);
        tB1.x = fmaf(w.y, xb4.x, tB1.x);
        tB1.y = fmaf(w.y, xb4.y, tB1.y);
        tB1.z = fmaf(w.y, xb4.z, tB1.z);
        tB1.w = fmaf(w.y, xb4.w, tB1.w);
        swA += w.x;
        swB += w.y;
    }

    float* o = ws + (long)blockIdx.x * (K * D) + k0 * D + d4;
    *reinterpret_cast<float4*>(o)       = make_float4(tA0.x - swA * cA0.x, tA0.y - swA * cA0.y,
                                                      tA0.z - swA * cA0.z, tA0.w - swA * cA0.w);
    *reinterpret_cast<float4*>(o + 64)  = make_float4(tA1.x - swA * cA1.x, tA1.y - swA * cA1.y,
                                                      tA1.z - swA * cA1.z, tA1.w - swA * cA1.w);
    *reinterpret_cast<float4*>(o + 128) = make_float4(tB0.x - swB * cB0.x, tB0.y - swB * cB0.y,
                                                      tB0.z - swB * cB0.z, tB0.w - swB * cB0.w);
    *reinterpret_cast<float4*>(o + 192) = make_float4(tB1.x - swB * cB1.x, tB1.y - swB * cB1.y,
                                                      tB1.z - swB * cB1.z, tB1.w - swB * cB1.w);
}

__global__ __launch_bounds__(256) void reduce2(
    const float* __restrict__ ws, float* __restrict__ out)
{
    __shared__ float4 part[32][8];

    const int tid   = threadIdx.x;
    const int col   = tid & 7;
    const int slice = tid >> 3;
    const int gcol  = blockIdx.x * 8 + col;

    const float4* P = reinterpret_cast<const float4*>(ws);  // [2048][1024]
    float4 acc = make_float4(0.f, 0.f, 0.f, 0.f);
    #pragma unroll 8
    for (int r = 0; r < 64; ++r) {
        float4 v = P[(long)(slice * 64 + r) * 1024 + gcol];
        acc.x += v.x; acc.y += v.y; acc.z += v.z; acc.w += v.w;
    }
    part[slice][col] = acc;
    __syncthreads();

    #pragma unroll
    for (int stride = 16; stride >= 1; stride >>= 1) {
        if (tid < stride * 8) {
            float4 a = part[slice][col];
            float4 b = part[slice + stride][col];
            a.x += b.x; a.y += b.y; a.z += b.z; a.w += b.w;
            part[slice][col] = a;
        }
        __syncthreads();
    }
    if (tid < 8) {
        reinterpret_cast<float4*>(out)[blockIdx.x * 8 + tid] = part[0][tid];
    }
}

extern "C" void kernel_launch(void* const* d_in, const int* in_sizes, int n_in,
                              void* d_out, int out_size, void* d_ws, size_t ws_size,
                              hipStream_t stream) {
    const float* x     = (const float*)d_in[0];
    const float* codes = (const float*)d_in[1];
    const float* scale = (const float*)d_in[2];
    float* out = (float*)d_out;
    float* ws  = (float*)d_ws;

    const size_t ws_coop = (size_t)CGRID * K * D * sizeof(float);  // 8 MB
    if (ws_size >= ws_coop) {
        void* args[] = { (void*)&x, (void*)&codes, (void*)&scale, (void*)&ws, (void*)&out };
        hipError_t err = hipLaunchCooperativeKernel(
            reinterpret_cast<void*>(enc_coop), dim3(CGRID), dim3(256), args, 0, stream);
        if (err == hipSuccess) return;
        // fall through to two-kernel path on failure
    }

    const size_t ws_needed = (size_t)GRID1 * K * D * sizeof(float);  // 32 MB
    if (ws_size >= ws_needed) {
        enc_partial<<<GRID1, 256, 0, stream>>>(x, codes, scale, ws);
        reduce2<<<128, 256, 0, stream>>>(ws, out);
    }
}

// Round 10
// 29.261 us; speedup vs baseline: 3.1117x; 3.1117x over previous
//
#include <hip/hip_runtime.h>

// Problem constants (fixed by the reference)
constexpr int N    = 16384;
constexpr int K    = 32;
constexpr int D    = 128;
constexpr int SPAD = K + 2;       // LDS score row stride (34)

// clang-native 4-float vector for nontemporal builtins (layout == float4)
typedef float f4 __attribute__((ext_vector_type(4)));

// ---- DPP helpers: butterfly add over 16-lane groups, pure VALU ----
template <int CTRL>
__device__ __forceinline__ float dpp_add(float v) {
    int j = __builtin_amdgcn_update_dpp(0, __float_as_int(v), CTRL, 0xF, 0xF, false);
    return v + __int_as_float(j);
}
__device__ __forceinline__ float sum16(float v) {
    v = dpp_add<0xB1>(v);    // quad_perm xor1
    v = dpp_add<0x4E>(v);    // quad_perm xor2
    v = dpp_add<0x141>(v);   // row_half_mirror
    v = dpp_add<0x140>(v);   // row_mirror
    return v;                // 16-lane sum in every lane of the group
}

// ------------------------------------------------------------------
// Stage 1: grid1 blocks x 256 threads. Each block processes
// nchunk x 8 rows (reg-resident, persistent accumulators) and writes
// ONE partial E tile (16 KB) to ws with non-temporal stores.
// grid1=512 -> 32 rows/block, ws = 8 MB, 2 blocks/CU.
// ------------------------------------------------------------------
__global__ __launch_bounds__(256) void enc_partial(
    const float* __restrict__ x,      // (N, D)
    const float* __restrict__ codes,  // (K, D)
    const float* __restrict__ scale,  // (K,)
    float* __restrict__ ws,           // (grid1, K*D)
    int nchunk)
{
    __shared__ float sc_lds[8][SPAD];
    __shared__ float w_lds[8][SPAD];

    const int tid = threadIdx.x;
    const int kg  = tid >> 4;    // 0..15 -> k0 = 2kg
    const int dg  = tid & 15;    // 0..15
    const int d4  = dg << 2;     // float4 at d4 and 64+d4
    const int k0  = kg << 1;

    // codes fragments (2 k's x 2 float4s) + scales, registers throughout
    const float4 cA0 = *reinterpret_cast<const float4*>(&codes[k0 * D + d4]);
    const float4 cA1 = *reinterpret_cast<const float4*>(&codes[k0 * D + 64 + d4]);
    const float4 cB0 = *reinterpret_cast<const float4*>(&codes[(k0 + 1) * D + d4]);
    const float4 cB1 = *reinterpret_cast<const float4*>(&codes[(k0 + 1) * D + 64 + d4]);
    const float sA = scale[k0];
    const float sB = scale[k0 + 1];

    // persistent partial accumulators across chunks
    float4 tA0 = make_float4(0.f, 0.f, 0.f, 0.f);
    float4 tA1 = tA0, tB0 = tA0, tB1 = tA0;
    float swA = 0.f, swB = 0.f;

    const float* xb = x + (long)blockIdx.x * nchunk * 8 * D;

    for (int c = 0; c < nchunk; ++c) {
        // ---- x chunk into registers: 8 rows x 2 float4 per thread ----
        float4 xr[8][2];
        const float* xc = xb + c * 8 * D;
        #pragma unroll
        for (int n = 0; n < 8; ++n) {
            xr[n][0] = *reinterpret_cast<const float4*>(xc + n * D + d4);
            xr[n][1] = *reinterpret_cast<const float4*>(xc + n * D + 64 + d4);
        }

        // ---- Phase 1: scores ----
        #pragma unroll
        for (int n = 0; n < 8; ++n) {
            const float4 xa = xr[n][0];
            const float4 xb4 = xr[n][1];
            float r;
            float pA0 = 0.f, pA1 = 0.f, pB0 = 0.f, pB1 = 0.f;
            r = xa.x - cA0.x;  pA0 = fmaf(r, r, pA0);
            r = xa.y - cA0.y;  pA1 = fmaf(r, r, pA1);
            r = xa.z - cA0.z;  pA0 = fmaf(r, r, pA0);
            r = xa.w - cA0.w;  pA1 = fmaf(r, r, pA1);
            r = xb4.x - cA1.x; pA0 = fmaf(r, r, pA0);
            r = xb4.y - cA1.y; pA1 = fmaf(r, r, pA1);
            r = xb4.z - cA1.z; pA0 = fmaf(r, r, pA0);
            r = xb4.w - cA1.w; pA1 = fmaf(r, r, pA1);
            r = xa.x - cB0.x;  pB0 = fmaf(r, r, pB0);
            r = xa.y - cB0.y;  pB1 = fmaf(r, r, pB1);
            r = xa.z - cB0.z;  pB0 = fmaf(r, r, pB0);
            r = xa.w - cB0.w;  pB1 = fmaf(r, r, pB1);
            r = xb4.x - cB1.x; pB0 = fmaf(r, r, pB0);
            r = xb4.y - cB1.y; pB1 = fmaf(r, r, pB1);
            r = xb4.z - cB1.z; pB0 = fmaf(r, r, pB0);
            r = xb4.w - cB1.w; pB1 = fmaf(r, r, pB1);
            float pA = sum16(pA0 + pA1);
            float pB = sum16(pB0 + pB1);
            if (dg == 0) {
                sc_lds[n][k0]     = sqrtf(pA) * sA;
                sc_lds[n][k0 + 1] = sqrtf(pB) * sB;
            }
        }
        __syncthreads();

        // ---- Softmax over K per row: 32 threads/row ----
        {
            const int row = tid >> 5;      // 0..7
            const int q   = tid & 31;
            float s = sc_lds[row][q];
            float m = s;
            m = fmaxf(m, __shfl_xor(m, 1));
            m = fmaxf(m, __shfl_xor(m, 2));
            m = fmaxf(m, __shfl_xor(m, 4));
            m = fmaxf(m, __shfl_xor(m, 8));
            m = fmaxf(m, __shfl_xor(m, 16));
            const float LOG2E = 1.44269504088896f;
            float e = exp2f((s - m) * LOG2E);
            float sum = e;
            sum += __shfl_xor(sum, 1);
            sum += __shfl_xor(sum, 2);
            sum += __shfl_xor(sum, 4);
            sum += __shfl_xor(sum, 8);
            sum += __shfl_xor(sum, 16);
            w_lds[row][q] = e * (1.0f / sum);
        }
        __syncthreads();

        // ---- Phase 2: accumulate T and S ----
        #pragma unroll
        for (int n = 0; n < 8; ++n) {
            const float2 w = *reinterpret_cast<const float2*>(&w_lds[n][k0]);
            const float4 xa = xr[n][0];
            const float4 xb4 = xr[n][1];
            tA0.x = fmaf(w.x, xa.x, tA0.x);
            tA0.y = fmaf(w.x, xa.y, tA0.y);
            tA0.z = fmaf(w.x, xa.z, tA0.z);
            tA0.w = fmaf(w.x, xa.w, tA0.w);
            tA1.x = fmaf(w.x, xb4.x, tA1.x);
            tA1.y = fmaf(w.x, xb4.y, tA1.y);
            tA1.z = fmaf(w.x, xb4.z, tA1.z);
            tA1.w = fmaf(w.x, xb4.w, tA1.w);
            tB0.x = fmaf(w.y, xa.x, tB0.x);
            tB0.y = fmaf(w.y, xa.y, tB0.y);
            tB0.z = fmaf(w.y, xa.z, tB0.z);
            tB0.w = fmaf(w.y, xa.w, tB0.w);
            tB1.x = fmaf(w.y, xb4.x, tB1.x);
            tB1.y = fmaf(w.y, xb4.y, tB1.y);
            tB1.z = fmaf(w.y, xb4.z, tB1.z);
            tB1.w = fmaf(w.y, xb4.w, tB1.w);
            swA += w.x;
            swB += w.y;
        }
        __syncthreads();   // protect sc_lds/w_lds before next chunk
    }

    // ---- Epilogue: partial E_b = T - S*c -> ws (non-temporal f4 stores) ----
    f4* o = reinterpret_cast<f4*>(ws + (long)blockIdx.x * (K * D) + k0 * D + d4);
    f4 e0 = { tA0.x - swA * cA0.x, tA0.y - swA * cA0.y,
              tA0.z - swA * cA0.z, tA0.w - swA * cA0.w };
    f4 e1 = { tA1.x - swA * cA1.x, tA1.y - swA * cA1.y,
              tA1.z - swA * cA1.z, tA1.w - swA * cA1.w };
    f4 e2 = { tB0.x - swB * cB0.x, tB0.y - swB * cB0.y,
              tB0.z - swB * cB0.z, tB0.w - swB * cB0.w };
    f4 e3 = { tB1.x - swB * cB1.x, tB1.y - swB * cB1.y,
              tB1.z - swB * cB1.z, tB1.w - swB * cB1.w };
    __builtin_nontemporal_store(e0, o);        // +0   floats
    __builtin_nontemporal_store(e1, o + 16);   // +64  floats
    __builtin_nontemporal_store(e2, o + 32);   // +128 floats
    __builtin_nontemporal_store(e3, o + 48);   // +192 floats
}

// ------------------------------------------------------------------
// Stage 2: column-sum ws[nrows][4096] -> out[4096].
// 256 blocks (full chip); block owns 4 float4-cols x all rows.
// Thread: col=tid&3, slice=tid>>2 (64 slices x nrows/64 rows each).
// Non-temporal loads; LDS tree; plain single-writer store.
// ------------------------------------------------------------------
__global__ __launch_bounds__(256) void reduce2(
    const float* __restrict__ ws, float* __restrict__ out, int nrows)
{
    __shared__ f4 part[64][4];     // 4 KB

    const int tid   = threadIdx.x;
    const int col   = tid & 3;
    const int slice = tid >> 2;                  // 0..63
    const int gcol  = blockIdx.x * 4 + col;      // 0..1023
    const int rpt   = nrows >> 6;                // rows per thread

    const f4* P = reinterpret_cast<const f4*>(ws);
    f4 acc = { 0.f, 0.f, 0.f, 0.f };
    long base = (long)slice * rpt * 1024 + gcol;
    for (int r = 0; r < rpt; ++r) {
        f4 v = __builtin_nontemporal_load(P + base + (long)r * 1024);
        acc += v;
    }
    part[slice][col] = acc;
    __syncthreads();

    #pragma unroll
    for (int stride = 32; stride >= 1; stride >>= 1) {
        if (tid < stride * 4) {
            part[slice][col] += part[slice + stride][col];
        }
        __syncthreads();
    }
    if (tid < 4) {
        reinterpret_cast<f4*>(out)[blockIdx.x * 4 + tid] = part[0][tid];
    }
}

extern "C" void kernel_launch(void* const* d_in, const int* in_sizes, int n_in,
                              void* d_out, int out_size, void* d_ws, size_t ws_size,
                              hipStream_t stream) {
    const float* x     = (const float*)d_in[0];
    const float* codes = (const float*)d_in[1];
    const float* scale = (const float*)d_in[2];
    float* out = (float*)d_out;
    float* ws  = (float*)d_ws;

    // Pick the largest supported partial grid that fits ws.
    // grid1 must divide N/8 and be a multiple of 64 (for reduce2).
    int grid1 = 512;                                   // 8 MB ws
    if (ws_size < (size_t)grid1 * K * D * sizeof(float)) grid1 = 128;  // 2 MB ws
    const int nchunk = N / (grid1 * 8);

    enc_partial<<<grid1, 256, 0, stream>>>(x, codes, scale, ws, nchunk);
    reduce2<<<256, 256, 0, stream>>>(ws, out, grid1);
}

// Round 11
// 28.109 us; speedup vs baseline: 3.2393x; 1.0410x over previous
//
#include <hip/hip_runtime.h>

// Problem constants (fixed by the reference)
constexpr int N    = 16384;
constexpr int K    = 32;
constexpr int D    = 128;
constexpr int SPAD = K + 2;       // LDS score row stride (34)

// clang-native 4-float vector for nontemporal builtins (layout == float4)
typedef float f4 __attribute__((ext_vector_type(4)));

// ---- DPP helpers: butterfly reduce over 16-lane groups, pure VALU ----
template <int CTRL>
__device__ __forceinline__ float dpp_add(float v) {
    int j = __builtin_amdgcn_update_dpp(0, __float_as_int(v), CTRL, 0xF, 0xF, false);
    return v + __int_as_float(j);
}
template <int CTRL>
__device__ __forceinline__ float dpp_max(float v) {
    int j = __builtin_amdgcn_update_dpp(0, __float_as_int(v), CTRL, 0xF, 0xF, false);
    return fmaxf(v, __int_as_float(j));
}
__device__ __forceinline__ float sum16(float v) {
    v = dpp_add<0xB1>(v);    // quad_perm xor1
    v = dpp_add<0x4E>(v);    // quad_perm xor2
    v = dpp_add<0x141>(v);   // row_half_mirror
    v = dpp_add<0x140>(v);   // row_mirror
    return v;
}
__device__ __forceinline__ float max16(float v) {
    v = dpp_max<0xB1>(v);
    v = dpp_max<0x4E>(v);
    v = dpp_max<0x141>(v);
    v = dpp_max<0x140>(v);
    return v;
}

// ------------------------------------------------------------------
// Stage 1: grid1 x 256, __launch_bounds__(256,4) -> 4 blocks/CU.
// Thread (kg,dg): k in {2kg,2kg+1}, d in {4dg..+3} u {64+4dg..+3}.
// dist^2 = ||x||^2 - 2 x.c + ||c||^2 (per-lane combine, one sum16).
// Softmax: DPP within 16 lanes + single shfl_xor(16) (2 bpermutes).
// Double-buffered score/weight LDS -> 2 barriers per 8-row chunk.
// ------------------------------------------------------------------
__global__ __launch_bounds__(256, 4) void enc_partial(
    const float* __restrict__ x,      // (N, D)
    const float* __restrict__ codes,  // (K, D)
    const float* __restrict__ scale,  // (K,)
    float* __restrict__ ws,           // (grid1, K*D)
    int nchunk)
{
    __shared__ float sc_lds[2][8][SPAD];   // raw sum(q) partial distances
    __shared__ float w_lds[2][8][SPAD];    // softmax weights
    __shared__ float cn2_lds[K];           // ||c_k||^2

    const int tid = threadIdx.x;
    const int kg  = tid >> 4;    // 0..15 -> k0 = 2kg
    const int dg  = tid & 15;    // 0..15
    const int d4  = dg << 2;     // float4 at d4 and 64+d4
    const int k0  = kg << 1;

    // codes fragments (2 k's x 2 float4s), registers throughout
    const float4 cA0 = *reinterpret_cast<const float4*>(&codes[k0 * D + d4]);
    const float4 cA1 = *reinterpret_cast<const float4*>(&codes[k0 * D + 64 + d4]);
    const float4 cB0 = *reinterpret_cast<const float4*>(&codes[(k0 + 1) * D + d4]);
    const float4 cB1 = *reinterpret_cast<const float4*>(&codes[(k0 + 1) * D + 64 + d4]);

    // ||c||^2 (full 128-d) via partial + sum16; park in LDS for softmax phase
    {
        float pa = 0.f, pb = 0.f;
        pa = fmaf(cA0.x, cA0.x, pa); pa = fmaf(cA0.y, cA0.y, pa);
        pa = fmaf(cA0.z, cA0.z, pa); pa = fmaf(cA0.w, cA0.w, pa);
        pa = fmaf(cA1.x, cA1.x, pa); pa = fmaf(cA1.y, cA1.y, pa);
        pa = fmaf(cA1.z, cA1.z, pa); pa = fmaf(cA1.w, cA1.w, pa);
        pb = fmaf(cB0.x, cB0.x, pb); pb = fmaf(cB0.y, cB0.y, pb);
        pb = fmaf(cB0.z, cB0.z, pb); pb = fmaf(cB0.w, cB0.w, pb);
        pb = fmaf(cB1.x, cB1.x, pb); pb = fmaf(cB1.y, cB1.y, pb);
        pb = fmaf(cB1.z, cB1.z, pb); pb = fmaf(cB1.w, cB1.w, pb);
        float cn2A = sum16(pa);
        float cn2B = sum16(pb);
        if (dg == 0) {
            cn2_lds[k0]     = cn2A;
            cn2_lds[k0 + 1] = cn2B;
        }
    }
    const float sclq = scale[tid & 31];    // scale for softmax lane (k=q)

    // persistent partial accumulators across chunks
    float4 tA0 = make_float4(0.f, 0.f, 0.f, 0.f);
    float4 tA1 = tA0, tB0 = tA0, tB1 = tA0;
    float swA = 0.f, swB = 0.f;

    const float* xb = x + (long)blockIdx.x * nchunk * 8 * D;

    for (int c = 0; c < nchunk; ++c) {
        const int p = c & 1;
        // ---- x chunk into registers: 8 rows x 2 float4 per thread ----
        float4 xr[8][2];
        const float* xc = xb + c * 8 * D;
        #pragma unroll
        for (int n = 0; n < 8; ++n) {
            xr[n][0] = *reinterpret_cast<const float4*>(xc + n * D + d4);
            xr[n][1] = *reinterpret_cast<const float4*>(xc + n * D + 64 + d4);
        }

        // ---- Phase 1: q = ||x||^2 - 2 x.c (partial), one sum16 per k ----
        #pragma unroll
        for (int n = 0; n < 8; ++n) {
            const float4 xa = xr[n][0];
            const float4 xb4 = xr[n][1];
            float nx = 0.f, dA = 0.f, dB = 0.f;
            nx = fmaf(xa.x, xa.x, nx);   nx = fmaf(xa.y, xa.y, nx);
            nx = fmaf(xa.z, xa.z, nx);   nx = fmaf(xa.w, xa.w, nx);
            nx = fmaf(xb4.x, xb4.x, nx); nx = fmaf(xb4.y, xb4.y, nx);
            nx = fmaf(xb4.z, xb4.z, nx); nx = fmaf(xb4.w, xb4.w, nx);
            dA = fmaf(xa.x, cA0.x, dA);  dA = fmaf(xa.y, cA0.y, dA);
            dA = fmaf(xa.z, cA0.z, dA);  dA = fmaf(xa.w, cA0.w, dA);
            dA = fmaf(xb4.x, cA1.x, dA); dA = fmaf(xb4.y, cA1.y, dA);
            dA = fmaf(xb4.z, cA1.z, dA); dA = fmaf(xb4.w, cA1.w, dA);
            dB = fmaf(xa.x, cB0.x, dB);  dB = fmaf(xa.y, cB0.y, dB);
            dB = fmaf(xa.z, cB0.z, dB);  dB = fmaf(xa.w, cB0.w, dB);
            dB = fmaf(xb4.x, cB1.x, dB); dB = fmaf(xb4.y, cB1.y, dB);
            dB = fmaf(xb4.z, cB1.z, dB); dB = fmaf(xb4.w, cB1.w, dB);
            float qA = fmaf(-2.f, dA, nx);
            float qB = fmaf(-2.f, dB, nx);
            qA = sum16(qA);
            qB = sum16(qB);
            if (dg == 0) {
                sc_lds[p][n][k0]     = qA;
                sc_lds[p][n][k0 + 1] = qB;
            }
        }
        __syncthreads();

        // ---- Softmax over K per row (32 threads/row, DPP + 1 shfl each) ----
        {
            const int row = tid >> 5;      // 0..7
            const int q   = tid & 31;
            float sq = sc_lds[p][row][q];
            float s  = sqrtf(fmaxf(sq + cn2_lds[q], 0.f)) * sclq;
            float m = max16(s);
            m = fmaxf(m, __shfl_xor(m, 16));
            float e = exp2f((s - m) * 1.44269504088896f);
            float sum = sum16(e);
            sum += __shfl_xor(sum, 16);
            w_lds[p][row][q] = e * (1.0f / sum);
        }
        __syncthreads();

        // ---- Phase 2: accumulate T and S (x from regs, w broadcast b64) ----
        #pragma unroll
        for (int n = 0; n < 8; ++n) {
            const float2 w = *reinterpret_cast<const float2*>(&w_lds[p][n][k0]);
            const float4 xa = xr[n][0];
            const float4 xb4 = xr[n][1];
            tA0.x = fmaf(w.x, xa.x, tA0.x);
            tA0.y = fmaf(w.x, xa.y, tA0.y);
            tA0.z = fmaf(w.x, xa.z, tA0.z);
            tA0.w = fmaf(w.x, xa.w, tA0.w);
            tA1.x = fmaf(w.x, xb4.x, tA1.x);
            tA1.y = fmaf(w.x, xb4.y, tA1.y);
            tA1.z = fmaf(w.x, xb4.z, tA1.z);
            tA1.w = fmaf(w.x, xb4.w, tA1.w);
            tB0.x = fmaf(w.y, xa.x, tB0.x);
            tB0.y = fmaf(w.y, xa.y, tB0.y);
            tB0.z = fmaf(w.y, xa.z, tB0.z);
            tB0.w = fmaf(w.y, xa.w, tB0.w);
            tB1.x = fmaf(w.y, xb4.x, tB1.x);
            tB1.y = fmaf(w.y, xb4.y, tB1.y);
            tB1.z = fmaf(w.y, xb4.z, tB1.z);
            tB1.w = fmaf(w.y, xb4.w, tB1.w);
            swA += w.x;
            swB += w.y;
        }
        // no trailing barrier: next chunk uses the other LDS buffer
    }

    // ---- Epilogue: partial E_b = T - S*c -> ws (non-temporal f4 stores) ----
    f4* o = reinterpret_cast<f4*>(ws + (long)blockIdx.x * (K * D) + k0 * D + d4);
    f4 e0 = { tA0.x - swA * cA0.x, tA0.y - swA * cA0.y,
              tA0.z - swA * cA0.z, tA0.w - swA * cA0.w };
    f4 e1 = { tA1.x - swA * cA1.x, tA1.y - swA * cA1.y,
              tA1.z - swA * cA1.z, tA1.w - swA * cA1.w };
    f4 e2 = { tB0.x - swB * cB0.x, tB0.y - swB * cB0.y,
              tB0.z - swB * cB0.z, tB0.w - swB * cB0.w };
    f4 e3 = { tB1.x - swB * cB1.x, tB1.y - swB * cB1.y,
              tB1.z - swB * cB1.z, tB1.w - swB * cB1.w };
    __builtin_nontemporal_store(e0, o);        // +0   floats
    __builtin_nontemporal_store(e1, o + 16);   // +64  floats
    __builtin_nontemporal_store(e2, o + 32);   // +128 floats
    __builtin_nontemporal_store(e3, o + 48);   // +192 floats
}

// ------------------------------------------------------------------
// Stage 2: column-sum ws[nrows][4096] -> out[4096].
// 256 blocks; block owns 4 float4-cols x all rows.
// Thread: col=tid&3, slice=tid>>2 (64 slices). NT loads; LDS tree;
// plain single-writer store. No atomics, no pre-zero.
// ------------------------------------------------------------------
__global__ __launch_bounds__(256) void reduce2(
    const float* __restrict__ ws, float* __restrict__ out, int nrows)
{
    __shared__ f4 part[64][4];     // 4 KB

    const int tid   = threadIdx.x;
    const int col   = tid & 3;
    const int slice = tid >> 2;                  // 0..63
    const int gcol  = blockIdx.x * 4 + col;      // 0..1023
    const int rpt   = nrows >> 6;                // rows per thread

    const f4* P = reinterpret_cast<const f4*>(ws);
    f4 acc = { 0.f, 0.f, 0.f, 0.f };
    long base = (long)slice * rpt * 1024 + gcol;
    for (int r = 0; r < rpt; ++r) {
        f4 v = __builtin_nontemporal_load(P + base + (long)r * 1024);
        acc += v;
    }
    part[slice][col] = acc;
    __syncthreads();

    #pragma unroll
    for (int stride = 32; stride >= 1; stride >>= 1) {
        if (tid < stride * 4) {
            part[slice][col] += part[slice + stride][col];
        }
        __syncthreads();
    }
    if (tid < 4) {
        reinterpret_cast<f4*>(out)[blockIdx.x * 4 + tid] = part[0][tid];
    }
}

extern "C" void kernel_launch(void* const* d_in, const int* in_sizes, int n_in,
                              void* d_out, int out_size, void* d_ws, size_t ws_size,
                              hipStream_t stream) {
    const float* x     = (const float*)d_in[0];
    const float* codes = (const float*)d_in[1];
    const float* scale = (const float*)d_in[2];
    float* out = (float*)d_out;
    float* ws  = (float*)d_ws;

    // grid1 must divide N/8 and be a multiple of 64 (for reduce2).
    int grid1 = 1024;                                  // 16 MB ws
    if (ws_size < (size_t)grid1 * K * D * sizeof(float)) grid1 = 512;   // 8 MB
    if (ws_size < (size_t)grid1 * K * D * sizeof(float)) grid1 = 128;   // 2 MB
    const int nchunk = N / (grid1 * 8);

    enc_partial<<<grid1, 256, 0, stream>>>(x, codes, scale, ws, nchunk);
    reduce2<<<256, 256, 0, stream>>>(ws, out, grid1);
}